// Round 1
// baseline (1533.673 us; speedup 1.0000x reference)
//
#include <hip/hip_runtime.h>

// CrossLayerTranscoder: encoder (res @ We^T -> JumpReLU -> feats) +
// cross-layer decoder (sum_l feats[l] @ Wd[p(l,l')]^T -> recon[l']).
// All GEMMs run as bf16 MFMA (16x16x32) with f32 accumulation.
// 128x128 tiles, BK=64, 256 threads (2x2 waves of 64x64).
// Reg-staged f32->bf16 LDS staging with XOR swizzle ((row&7)<<4) on both
// write and read sides -> conflict-free ds_read_b128 fragments.

#define MT 2048   // B*S
#define HD 1024   // H
#define FD 4096   // F
#define LL 8      // L

typedef __attribute__((ext_vector_type(8))) short short8;
typedef __attribute__((ext_vector_type(4))) float f32x4;

__device__ __forceinline__ unsigned int f2bf1(float x) {
  unsigned u = __float_as_uint(x);
  return (u + 0x7FFFu + ((u >> 16) & 1u)) >> 16;   // RNE f32->bf16
}

// Load a 128x64 f32 tile (row stride ld) into 8 float4 regs per thread.
__device__ __forceinline__ void load_tile(const float* __restrict__ base, int ld,
                                          float4* r) {
  const int t = threadIdx.x;
#pragma unroll
  for (int i = 0; i < 8; ++i) {
    int idx = t + 256 * i;
    int row = idx >> 4;      // 16 float4 per 64-col row
    int c4  = idx & 15;
    r[i] = *(const float4*)(base + (size_t)row * ld + c4 * 4);
  }
}

// Convert 8 float4 regs to bf16 and write 128x64 bf16 tile into LDS, swizzled.
__device__ __forceinline__ void write_tile(char* lds, const float4* r) {
  const int t = threadIdx.x;
#pragma unroll
  for (int i = 0; i < 8; ++i) {
    int idx = t + 256 * i;
    int row = idx >> 4;
    int c4  = idx & 15;
    int off = (row * 128 + c4 * 8) ^ ((row & 7) << 4);
    unsigned lo = f2bf1(r[i].x) | (f2bf1(r[i].y) << 16);
    unsigned hi = f2bf1(r[i].z) | (f2bf1(r[i].w) << 16);
    *(uint2*)(lds + off) = make_uint2(lo, hi);
  }
}

// One BK=64 step: 2 x (read frags + 16 MFMA).
__device__ __forceinline__ void compute_tile(const char* sA, const char* sB,
                                             f32x4 acc[4][4], int wr, int wc,
                                             int l16, int h16) {
#pragma unroll
  for (int ks = 0; ks < 2; ++ks) {
    short8 a[4], b[4];
#pragma unroll
    for (int i = 0; i < 4; ++i) {
      int row = wr * 64 + i * 16 + l16;
      a[i] = *(const short8*)(sA + ((row * 128 + ks * 64 + h16 * 16) ^ ((row & 7) << 4)));
    }
#pragma unroll
    for (int j = 0; j < 4; ++j) {
      int col = wc * 64 + j * 16 + l16;
      b[j] = *(const short8*)(sB + ((col * 128 + ks * 64 + h16 * 16) ^ ((col & 7) << 4)));
    }
#pragma unroll
    for (int i = 0; i < 4; ++i)
#pragma unroll
      for (int j = 0; j < 4; ++j)
        acc[i][j] = __builtin_amdgcn_mfma_f32_16x16x32_bf16(a[i], b[j], acc[i][j], 0, 0, 0);
  }
}

// ---------------- Encoder: feats[l] = jumprelu(res[l] @ We[l]^T + be[l]) ---
__global__ __launch_bounds__(256, 2) void enc_kernel(
    const float* __restrict__ res, const float* __restrict__ We,
    const float* __restrict__ be, const float* __restrict__ thresh,
    float* __restrict__ feats) {
  __shared__ char sA[128 * 64 * 2];
  __shared__ char sB[128 * 64 * 2];

  const int l  = blockIdx.z;
  const int m0 = blockIdx.y * 128;
  const int f0 = blockIdx.x * 128;

  const float* Abase = res + (size_t)l * MT * HD + (size_t)m0 * HD;
  const float* Bbase = We  + (size_t)l * FD * HD + (size_t)f0 * HD;

  const int t = threadIdx.x;
  const int lane = t & 63, wave = t >> 6;
  const int wr = wave >> 1, wc = wave & 1;
  const int l16 = lane & 15, h16 = lane >> 4;

  f32x4 acc[4][4];
#pragma unroll
  for (int i = 0; i < 4; ++i)
#pragma unroll
    for (int j = 0; j < 4; ++j) acc[i][j] = (f32x4){0.f, 0.f, 0.f, 0.f};

  float4 ra[8], rb[8];
  load_tile(Abase, HD, ra);
  load_tile(Bbase, HD, rb);

  const int NK = HD / 64;
  for (int kt = 0; kt < NK; ++kt) {
    write_tile(sA, ra);
    write_tile(sB, rb);
    __syncthreads();
    if (kt + 1 < NK) {
      load_tile(Abase + (kt + 1) * 64, HD, ra);   // overlaps with MFMA phase
      load_tile(Bbase + (kt + 1) * 64, HD, rb);
    }
    compute_tile(sA, sB, acc, wr, wc, l16, h16);
    __syncthreads();
  }

  const float th = thresh[l];
#pragma unroll
  for (int j = 0; j < 4; ++j) {
    int col = f0 + wc * 64 + j * 16 + l16;
    float bev = be[(size_t)l * FD + col];
#pragma unroll
    for (int i = 0; i < 4; ++i) {
      int rbase = m0 + wr * 64 + i * 16 + h16 * 4;
#pragma unroll
      for (int q = 0; q < 4; ++q) {
        float v = acc[i][j][q] + bev;
        feats[((size_t)l * MT + rbase + q) * FD + col] = (v > th) ? v : 0.f;
      }
    }
  }
}

// ---------------- Decoder: recon[l'] = sum_{l<=l'} feats[l] @ Wd[p]^T + bd --
__global__ __launch_bounds__(256, 2) void dec_kernel(
    const float* __restrict__ feats, const float* __restrict__ Wd,
    const float* __restrict__ bd, float* __restrict__ recon) {
  __shared__ char sA[128 * 64 * 2];
  __shared__ char sB[128 * 64 * 2];

  const int lp = (LL - 1) - (int)blockIdx.z;  // heavy blocks (lp=7) first
  const int m0 = blockIdx.y * 128;
  const int h0 = blockIdx.x * 128;

  const int t = threadIdx.x;
  const int lane = t & 63, wave = t >> 6;
  const int wr = wave >> 1, wc = wave & 1;
  const int l16 = lane & 15, h16 = lane >> 4;

  f32x4 acc[4][4];
#pragma unroll
  for (int i = 0; i < 4; ++i)
#pragma unroll
    for (int j = 0; j < 4; ++j) acc[i][j] = (f32x4){0.f, 0.f, 0.f, 0.f};

  const int nit = (lp + 1) * (FD / 64);   // flattened (l, kt) loop

  // iteration -> global base pointers
  auto Ab = [&](int it) -> const float* {
    int l = it >> 6, kt = it & 63;
    return feats + ((size_t)l * MT + m0) * FD + kt * 64;
  };
  auto Bb = [&](int it) -> const float* {
    int l = it >> 6, kt = it & 63;
    int p = l * LL - l * (l - 1) / 2 + (lp - l);
    return Wd + ((size_t)p * HD + h0) * FD + kt * 64;
  };

  float4 ra[8], rb[8];
  load_tile(Ab(0), FD, ra);
  load_tile(Bb(0), FD, rb);

  for (int it = 0; it < nit; ++it) {
    write_tile(sA, ra);
    write_tile(sB, rb);
    __syncthreads();
    if (it + 1 < nit) {
      load_tile(Ab(it + 1), FD, ra);   // overlaps with MFMA phase
      load_tile(Bb(it + 1), FD, rb);
    }
    compute_tile(sA, sB, acc, wr, wc, l16, h16);
    __syncthreads();
  }

#pragma unroll
  for (int j = 0; j < 4; ++j) {
    int col = h0 + wc * 64 + j * 16 + l16;
    float bsum = 0.f;
    for (int l = 0; l <= lp; ++l) {
      int p = l * LL - l * (l - 1) / 2 + (lp - l);
      bsum += bd[(size_t)p * HD + col];
    }
#pragma unroll
    for (int i = 0; i < 4; ++i) {
      int rbase = m0 + wr * 64 + i * 16 + h16 * 4;
#pragma unroll
      for (int q = 0; q < 4; ++q) {
        recon[((size_t)lp * MT + rbase + q) * HD + col] = acc[i][j][q] + bsum;
      }
    }
  }
}

extern "C" void kernel_launch(void* const* d_in, const int* in_sizes, int n_in,
                              void* d_out, int out_size, void* d_ws, size_t ws_size,
                              hipStream_t stream) {
  const float* res    = (const float*)d_in[0];
  const float* We     = (const float*)d_in[1];
  const float* be     = (const float*)d_in[2];
  const float* Wd     = (const float*)d_in[3];
  const float* bd     = (const float*)d_in[4];
  const float* thresh = (const float*)d_in[5];

  float* recon = (float*)d_out;                       // L*M*H
  float* feats = recon + (size_t)LL * MT * HD;        // L*M*F

  dim3 blk(256);
  enc_kernel<<<dim3(FD / 128, MT / 128, LL), blk, 0, stream>>>(res, We, be, thresh, feats);
  dec_kernel<<<dim3(HD / 128, MT / 128, LL), blk, 0, stream>>>(feats, Wd, bd, recon);
}

// Round 2
// 1257.005 us; speedup vs baseline: 1.2201x; 1.2201x over previous
//
#include <hip/hip_runtime.h>

// CrossLayerTranscoder: encoder (res @ We^T -> JumpReLU -> feats) +
// cross-layer decoder (sum_l feats[l] @ Wd[p(l,l')]^T -> recon[l']).
// bf16 MFMA (16x16x32), f32 accum. 128x128 tiles, BK=64, 256 threads.
// R2: encoder dual-writes feats as bf16 into d_ws; decoder reads bf16 A
// (halves the dominant fetch stream; per-lp working set becomes L3-resident).
// XOR-swizzled LDS ((row&7)<<4) on write+read -> conflict-free ds_read_b128.

#define MT 2048   // B*S
#define HD 1024   // H
#define FD 4096   // F
#define LL 8      // L

typedef __attribute__((ext_vector_type(8))) short short8;
typedef __attribute__((ext_vector_type(4))) float f32x4;

__device__ __forceinline__ unsigned int f2bf1(float x) {
  unsigned u = __float_as_uint(x);
  return (u + 0x7FFFu + ((u >> 16) & 1u)) >> 16;   // RNE f32->bf16
}

// ---- f32 tile staging (128x64, row stride ld), reg-staged ----------------
__device__ __forceinline__ void load_tile(const float* __restrict__ base, int ld,
                                          float4* r) {
  const int t = threadIdx.x;
#pragma unroll
  for (int i = 0; i < 8; ++i) {
    int idx = t + 256 * i;
    int row = idx >> 4;      // 16 float4 per 64-col row
    int c4  = idx & 15;
    r[i] = *(const float4*)(base + (size_t)row * ld + c4 * 4);
  }
}

__device__ __forceinline__ void write_tile(char* lds, const float4* r) {
  const int t = threadIdx.x;
#pragma unroll
  for (int i = 0; i < 8; ++i) {
    int idx = t + 256 * i;
    int row = idx >> 4;
    int c4  = idx & 15;
    int off = (row * 128 + c4 * 8) ^ ((row & 7) << 4);
    unsigned lo = f2bf1(r[i].x) | (f2bf1(r[i].y) << 16);
    unsigned hi = f2bf1(r[i].z) | (f2bf1(r[i].w) << 16);
    *(uint2*)(lds + off) = make_uint2(lo, hi);
  }
}

// ---- bf16 tile staging (128x64, row stride ld elements) ------------------
__device__ __forceinline__ void load_tile_bf(const unsigned short* __restrict__ base,
                                             int ld, short8* r) {
  const int t = threadIdx.x;
#pragma unroll
  for (int i = 0; i < 4; ++i) {
    int idx = t + 256 * i;
    int row = idx >> 3;      // 8 chunks of 8 bf16 per 64-col row
    int c8  = idx & 7;
    r[i] = *(const short8*)(base + (size_t)row * ld + c8 * 8);
  }
}

__device__ __forceinline__ void write_tile_bf(char* lds, const short8* r) {
  const int t = threadIdx.x;
#pragma unroll
  for (int i = 0; i < 4; ++i) {
    int idx = t + 256 * i;
    int row = idx >> 3;
    int c8  = idx & 7;
    int off = (row * 128 + c8 * 16) ^ ((row & 7) << 4);
    *(short8*)(lds + off) = r[i];
  }
}

// One BK=64 step: 2 x (read frags + 16 MFMA).
__device__ __forceinline__ void compute_tile(const char* sA, const char* sB,
                                             f32x4 acc[4][4], int wr, int wc,
                                             int l16, int h16) {
#pragma unroll
  for (int ks = 0; ks < 2; ++ks) {
    short8 a[4], b[4];
#pragma unroll
    for (int i = 0; i < 4; ++i) {
      int row = wr * 64 + i * 16 + l16;
      a[i] = *(const short8*)(sA + ((row * 128 + ks * 64 + h16 * 16) ^ ((row & 7) << 4)));
    }
#pragma unroll
    for (int j = 0; j < 4; ++j) {
      int col = wc * 64 + j * 16 + l16;
      b[j] = *(const short8*)(sB + ((col * 128 + ks * 64 + h16 * 16) ^ ((col & 7) << 4)));
    }
#pragma unroll
    for (int i = 0; i < 4; ++i)
#pragma unroll
      for (int j = 0; j < 4; ++j)
        acc[i][j] = __builtin_amdgcn_mfma_f32_16x16x32_bf16(a[i], b[j], acc[i][j], 0, 0, 0);
  }
}

// ---------------- Encoder: feats[l] = jumprelu(res[l] @ We[l]^T + be[l]) ---
__global__ __launch_bounds__(256, 2) void enc_kernel(
    const float* __restrict__ res, const float* __restrict__ We,
    const float* __restrict__ be, const float* __restrict__ thresh,
    float* __restrict__ feats, unsigned short* __restrict__ feats_bf) {
  __shared__ char sA[128 * 64 * 2];
  __shared__ char sB[128 * 64 * 2];

  const int l  = blockIdx.z;
  const int m0 = blockIdx.y * 128;
  const int f0 = blockIdx.x * 128;

  const float* Abase = res + (size_t)l * MT * HD + (size_t)m0 * HD;
  const float* Bbase = We  + (size_t)l * FD * HD + (size_t)f0 * HD;

  const int t = threadIdx.x;
  const int lane = t & 63, wave = t >> 6;
  const int wr = wave >> 1, wc = wave & 1;
  const int l16 = lane & 15, h16 = lane >> 4;

  f32x4 acc[4][4];
#pragma unroll
  for (int i = 0; i < 4; ++i)
#pragma unroll
    for (int j = 0; j < 4; ++j) acc[i][j] = (f32x4){0.f, 0.f, 0.f, 0.f};

  float4 ra[8], rb[8];
  load_tile(Abase, HD, ra);
  load_tile(Bbase, HD, rb);

  const int NK = HD / 64;
  for (int kt = 0; kt < NK; ++kt) {
    write_tile(sA, ra);
    write_tile(sB, rb);
    __syncthreads();
    if (kt + 1 < NK) {
      load_tile(Abase + (kt + 1) * 64, HD, ra);   // overlaps with MFMA phase
      load_tile(Bbase + (kt + 1) * 64, HD, rb);
    }
    compute_tile(sA, sB, acc, wr, wc, l16, h16);
    __syncthreads();
  }

  const float th = thresh[l];
#pragma unroll
  for (int j = 0; j < 4; ++j) {
    int col = f0 + wc * 64 + j * 16 + l16;
    float bev = be[(size_t)l * FD + col];
#pragma unroll
    for (int i = 0; i < 4; ++i) {
      int rbase = m0 + wr * 64 + i * 16 + h16 * 4;
#pragma unroll
      for (int q = 0; q < 4; ++q) {
        float v = acc[i][j][q] + bev;
        float g = (v > th) ? v : 0.f;
        size_t idx = ((size_t)l * MT + rbase + q) * FD + col;
        feats[idx] = g;
        if (feats_bf) feats_bf[idx] = (unsigned short)f2bf1(g);
      }
    }
  }
}

// ---------------- Decoder: recon[l'] = sum_{l<=l'} feats[l] @ Wd[p]^T + bd --
template <bool ABF16>
__global__ __launch_bounds__(256, 2) void dec_kernel(
    const float* __restrict__ feats_f32, const unsigned short* __restrict__ feats_bf,
    const float* __restrict__ Wd, const float* __restrict__ bd,
    float* __restrict__ recon) {
  __shared__ char sA[128 * 64 * 2];
  __shared__ char sB[128 * 64 * 2];

  const int lp = (LL - 1) - (int)blockIdx.z;  // heavy blocks (lp=7) first
  const int m0 = blockIdx.y * 128;
  const int h0 = blockIdx.x * 128;

  const int t = threadIdx.x;
  const int lane = t & 63, wave = t >> 6;
  const int wr = wave >> 1, wc = wave & 1;
  const int l16 = lane & 15, h16 = lane >> 4;

  f32x4 acc[4][4];
#pragma unroll
  for (int i = 0; i < 4; ++i)
#pragma unroll
    for (int j = 0; j < 4; ++j) acc[i][j] = (f32x4){0.f, 0.f, 0.f, 0.f};

  const int nit = (lp + 1) * (FD / 64);   // flattened (l, kt) loop

  auto Abf = [&](int it) -> const unsigned short* {
    int l = it >> 6, kt = it & 63;
    return feats_bf + ((size_t)l * MT + m0) * FD + kt * 64;
  };
  auto Af = [&](int it) -> const float* {
    int l = it >> 6, kt = it & 63;
    return feats_f32 + ((size_t)l * MT + m0) * FD + kt * 64;
  };
  auto Bb = [&](int it) -> const float* {
    int l = it >> 6, kt = it & 63;
    int p = l * LL - l * (l - 1) / 2 + (lp - l);
    return Wd + ((size_t)p * HD + h0) * FD + kt * 64;
  };

  short8 rab[4];
  float4 raf[8];
  float4 rb[8];
  if constexpr (ABF16) load_tile_bf(Abf(0), FD, rab); else load_tile(Af(0), FD, raf);
  load_tile(Bb(0), FD, rb);

  for (int it = 0; it < nit; ++it) {
    if constexpr (ABF16) write_tile_bf(sA, rab); else write_tile(sA, raf);
    write_tile(sB, rb);
    __syncthreads();
    if (it + 1 < nit) {
      if constexpr (ABF16) load_tile_bf(Abf(it + 1), FD, rab);
      else                 load_tile(Af(it + 1), FD, raf);
      load_tile(Bb(it + 1), FD, rb);      // overlaps with MFMA phase
    }
    compute_tile(sA, sB, acc, wr, wc, l16, h16);
    __syncthreads();
  }

#pragma unroll
  for (int j = 0; j < 4; ++j) {
    int col = h0 + wc * 64 + j * 16 + l16;
    float bsum = 0.f;
    for (int l = 0; l <= lp; ++l) {
      int p = l * LL - l * (l - 1) / 2 + (lp - l);
      bsum += bd[(size_t)p * HD + col];
    }
#pragma unroll
    for (int i = 0; i < 4; ++i) {
      int rbase = m0 + wr * 64 + i * 16 + h16 * 4;
#pragma unroll
      for (int q = 0; q < 4; ++q) {
        recon[((size_t)lp * MT + rbase + q) * HD + col] = acc[i][j][q] + bsum;
      }
    }
  }
}

extern "C" void kernel_launch(void* const* d_in, const int* in_sizes, int n_in,
                              void* d_out, int out_size, void* d_ws, size_t ws_size,
                              hipStream_t stream) {
  const float* res    = (const float*)d_in[0];
  const float* We     = (const float*)d_in[1];
  const float* be     = (const float*)d_in[2];
  const float* Wd     = (const float*)d_in[3];
  const float* bd     = (const float*)d_in[4];
  const float* thresh = (const float*)d_in[5];

  float* recon = (float*)d_out;                       // L*M*H
  float* feats = recon + (size_t)LL * MT * HD;        // L*M*F

  const size_t featsbf_bytes = (size_t)LL * MT * FD * sizeof(unsigned short); // 128 MiB
  const bool use_bf = ws_size >= featsbf_bytes;
  unsigned short* feats_bf = use_bf ? (unsigned short*)d_ws : nullptr;

  dim3 blk(256);
  enc_kernel<<<dim3(FD / 128, MT / 128, LL), blk, 0, stream>>>(res, We, be, thresh,
                                                               feats, feats_bf);
  if (use_bf)
    dec_kernel<true><<<dim3(HD / 128, MT / 128, LL), blk, 0, stream>>>(feats, feats_bf,
                                                                       Wd, bd, recon);
  else
    dec_kernel<false><<<dim3(HD / 128, MT / 128, LL), blk, 0, stream>>>(feats, nullptr,
                                                                        Wd, bd, recon);
}